// Round 1
// 95.871 us; speedup vs baseline: 1.0132x; 1.0132x over previous
//
#include <hip/hip_runtime.h>

#define GDIM   256
#define NCOLS  1024          // 16 x 16 x 4 columns of 16 x 16 x 64 voxels
#define CAP    128           // entries per (mask,column); mean ~32, Poisson tail negligible
#define NQ     2048          // u64 per column byte-grid (16*16*64 / 8)

// One thread per (mask, atom): push packed voxel index into every column the
// [i-2, i+2]^3 footprint touches (x,y tiles of 16; z tiles of 64; avg 1.66 columns).
__global__ void bin_kernel(const float* __restrict__ src,
                           const float* __restrict__ tgt,
                           const float* __restrict__ ox,
                           const float* __restrict__ oy,
                           const float* __restrict__ oz,
                           const float* __restrict__ vox,
                           unsigned* __restrict__ cnt,
                           unsigned* __restrict__ entries,
                           float* __restrict__ out,
                           int N)
{
    int tid = blockIdx.x * blockDim.x + threadIdx.x;
    if (tid == 0) *out = 0.0f;                    // ordered before tile_kernel's atomicAdds
    if (tid >= 2 * N) return;
    int a = tid % N;            // consecutive lanes -> coalesced coord loads
    int m = tid / N;            // 0 = src, 1 = tgt

    const float* c = m ? tgt : src;
    float vx = vox[0];
    int i0 = (int)floorf((c[a]         - ox[0]) / vx);
    int i1 = (int)floorf((c[N + a]     - oy[0]) / vx);
    int i2 = (int)floorf((c[2 * N + a] - oz[0]) / vx);
    if ((unsigned)i0 >= GDIM || (unsigned)i1 >= GDIM || (unsigned)i2 >= GDIM) return; // center_ok

    unsigned pk = (unsigned)i0 | ((unsigned)i1 << 8) | ((unsigned)i2 << 16);
    int tlx = max(i0 - 2, 0) >> 4, thx = min(i0 + 2, GDIM - 1) >> 4;
    int tly = max(i1 - 2, 0) >> 4, thy = min(i1 + 2, GDIM - 1) >> 4;
    int tlz = max(i2 - 2, 0) >> 6, thz = min(i2 + 2, GDIM - 1) >> 6;

    for (int tx = tlx; tx <= thx; ++tx)
        for (int ty = tly; ty <= thy; ++ty)
            for (int tz = tlz; tz <= thz; ++tz) {
                int bin = m * NCOLS + (((tx << 4) + ty) << 2) + tz;
                unsigned slot = atomicAdd(&cnt[bin], 1u);
                if (slot < CAP) entries[bin * CAP + slot] = pk;
            }
}

// One block per 16x16x64 column: zero LDS src+tgt byte-grids (32 KiB), splat staged
// entries (one thread per entry, 21 offsets unrolled with LITERAL patterns -> no
// table loads, no div/mod), then a BRANCHLESS SWAR scan: per-byte min-d2 via
// lsb-isolate + popcounts (no divergent while loop, no dependent LDS tbl reads).
// Cross term (src AND tgt cover same byte, ~0.85% of bytes) handled in a rare loop
// with one LDS read from a 49-entry product table.
__global__ __launch_bounds__(256, 4)
void tile_kernel(const unsigned* __restrict__ cnt,
                 const unsigned* __restrict__ entries,
                 float* __restrict__ out)
{
    __shared__ unsigned long long smem[2 * NQ];   // [0,NQ) src, [NQ,2NQ) tgt : 32 KiB
    __shared__ unsigned eS[CAP], eT[CAP];
    __shared__ float tblp[49];                    // tblp[a*7+b] = exp(-K a) * exp(-K b)
    __shared__ float wsum[4];

    // 21 (o0,o1) offsets with o0^2+o1^2 <= 5, as compile-time constants.
    constexpr int OX[21] = {-2,-2,-2,-1,-1,-1,-1,-1, 0, 0, 0, 0, 0, 1, 1, 1, 1, 1, 2, 2, 2};
    constexpr int OY[21] = {-1, 0, 1,-2,-1, 0, 1, 2,-2,-1, 0, 1, 2,-2,-1, 0, 1, 2,-1, 0, 1};
    // Packed 5-byte z-row patterns: byte k (LE) = offset o2 = k-2, value (1 << d2) if d2 <= 6.
    constexpr unsigned long long PATC[21] = {
        0x0040204000ull, 0x0020102000ull, 0x0040204000ull,
        0x0040204000ull, 0x4008040840ull, 0x2004020420ull, 0x4008040840ull, 0x0040204000ull,
        0x0020102000ull, 0x2004020420ull, 0x1002010210ull, 0x2004020420ull, 0x0020102000ull,
        0x0040204000ull, 0x4008040840ull, 0x2004020420ull, 0x4008040840ull, 0x0040204000ull,
        0x0040204000ull, 0x0020102000ull, 0x0040204000ull,
    };

    int tid = threadIdx.x;
    int t   = blockIdx.x;
    int cx0 = (t >> 6) << 4;
    int cy0 = ((t >> 2) & 15) << 4;
    int cz0 = (t & 3) << 6;

    const float kf = (float)((3.14159265358979323846 / 3.5) * (3.14159265358979323846 / 3.5));
    if (tid < 49) {
        int a = tid / 7, b = tid - 7 * a;
        tblp[tid] = expf(-kf * (float)a) * expf(-kf * (float)b);
    }
    {   // zero 32 KiB of LDS: 2048 uint4
        uint4* zp = (uint4*)smem;
        #pragma unroll
        for (int i = 0; i < 8; ++i) zp[tid + i * 256] = make_uint4(0u, 0u, 0u, 0u);
    }
    int nS = min(cnt[t],         (unsigned)CAP);
    int nT = min(cnt[NCOLS + t], (unsigned)CAP);
    if (tid < nS) eS[tid] = entries[t * CAP + tid];              // nS,nT <= 128 < 256
    if (tid < nT) eT[tid] = entries[(NCOLS + t) * CAP + tid];
    __syncthreads();

    // ---- splat: one thread per staged entry (nS+nT <= 256), 21 offsets unrolled ----
    if (tid < nS + nT) {
        int m        = tid >= nS;
        unsigned pk  = m ? eT[tid - nS] : eS[tid];
        int i0 = pk & 255, i1 = (pk >> 8) & 255, i2 = (pk >> 16) & 255;
        int zs   = max(i2 - 2, cz0), ze = min(i2 + 2, cz0 + 63); // binned => zs <= ze
        int drop = zs - (i2 - 2), keep = ze - zs + 1;            // keep in [1,5]
        int zb   = zs - cz0;
        int off  = zb & 7;
        unsigned long long kmask = (1ull << (8 * keep)) - 1ull;
        int x0 = i0 - cx0, y0 = i1 - cy0;
        unsigned long long* base = smem + m * NQ;
        bool spill = (off + keep) > 8;                           // off >= 4 when true
        #pragma unroll
        for (int r = 0; r < 21; ++r) {
            int l0 = x0 + OX[r]; if ((unsigned)l0 >= 16u) continue;  // column bounds == global clip
            int l1 = y0 + OY[r]; if ((unsigned)l1 >= 16u) continue;
            unsigned long long pat = (PATC[r] >> (8 * drop)) & kmask;
            if (!pat) continue;
            unsigned long long* q = base + (((l0 << 10) | (l1 << 6) | zb) >> 3);
            unsigned long long lo = pat << (8 * off);
            if (lo) atomicOr(q, lo);
            if (spill) {
                unsigned long long hi = pat >> (8 * (8 - off));  // shift in [8,32], no UB
                if (hi) atomicOr(q + 1, hi);
            }
        }
    }
    __syncthreads();

    // ---- scan: branchless SWAR min-d2 histogram + rare cross-term loop ----
    const unsigned long long H  = 0x8080808080808080ull;
    const unsigned long long B1 = 0x0101010101010101ull;
    const unsigned long long K7 = 0x7f7f7f7f7f7f7f7full;
    const ulonglong2* sp = (const ulonglong2*)smem;
    const ulonglong2* tp = (const ulonglong2*)(smem + NQ);

    ulonglong2 sv[4], tw[4];                       // issue all 8 ds_read_b128 up front
    #pragma unroll
    for (int i = 0; i < 4; ++i) {
        sv[i] = sp[tid + i * 256];
        tw[i] = tp[tid + i * 256];
    }

    int cd[7] = {0, 0, 0, 0, 0, 0, 0};             // static-indexed -> registers
    float accC = 0.0f;
    #pragma unroll
    for (int i = 0; i < 4; ++i) {
        #pragma unroll
        for (int k = 0; k < 2; ++k) {
            unsigned long long w = k ? sv[i].y : sv[i].x;
            unsigned long long v = k ? tw[i].y : tw[i].x;
            // per-byte lowest set bit (data bytes <= 0x7F; empty byte -> 0x80 sentinel)
            unsigned long long q   = w | H;
            unsigned long long lsb = q & (~q + B1);              // no cross-byte carries
            #pragma unroll
            for (int d = 0; d < 7; ++d)
                cd[d] += __popcll(lsb & (B1 << d));              // bytes with min d2 == d
            // bytes where BOTH src and tgt are covered (rare): subtract vs*vt
            unsigned long long bth = ((w + K7) & H) & ((v + K7) & H);
            while (bth) {
                int bit = __ffsll((long long)bth) - 1;           // = 8*byte + 7
                int sh  = bit & ~7;
                int ds  = __ffs((int)((unsigned)(w >> sh) & 0x7fu)) - 1;
                int dt  = __ffs((int)((unsigned)(v >> sh) & 0x7fu)) - 1;
                accC += tblp[ds * 7 + dt];
                bth &= bth - 1;
            }
        }
    }
    float acc = -accC;
    #pragma unroll
    for (int d = 0; d < 7; ++d) {
        float tv = expf(-kf * (float)d);           // same device expf values as tblp
        acc = fmaf((float)cd[d], tv * tv, acc);    // + count_d * tbl[d]^2
    }

    #pragma unroll
    for (int off2 = 32; off2 > 0; off2 >>= 1)
        acc += __shfl_down(acc, off2, 64);
    int lane = tid & 63, wv = tid >> 6;
    if (lane == 0) wsum[wv] = acc;
    __syncthreads();
    if (tid == 0)
        atomicAdd(out, wsum[0] + wsum[1] + wsum[2] + wsum[3]);
}

extern "C" void kernel_launch(void* const* d_in, const int* in_sizes, int n_in,
                              void* d_out, int out_size, void* d_ws, size_t ws_size,
                              hipStream_t stream)
{
    const float* src = (const float*)d_in[0];   // (1,3,N): [dim][atom]
    const float* tgt = (const float*)d_in[1];
    const float* ox  = (const float*)d_in[2];
    const float* oy  = (const float*)d_in[3];
    const float* oz  = (const float*)d_in[4];
    const float* vox = (const float*)d_in[5];
    int N = in_sizes[0] / 3;

    unsigned* cnt     = (unsigned*)d_ws;                 // 2*1024 counters (8 KiB)
    unsigned* entries = cnt + 2 * NCOLS;                 // 2*1024*128 u32 (1 MiB)

    hipMemsetAsync(cnt, 0, 2 * NCOLS * sizeof(unsigned), stream);

    int nb = (2 * N + 255) / 256;
    bin_kernel<<<nb, 256, 0, stream>>>(src, tgt, ox, oy, oz, vox, cnt, entries,
                                       (float*)d_out, N);
    tile_kernel<<<NCOLS, 256, 0, stream>>>(cnt, entries, (float*)d_out);
}

// Round 2
// 93.220 us; speedup vs baseline: 1.0420x; 1.0284x over previous
//
#include <hip/hip_runtime.h>

#define GDIM   256
#define NCOLS  1024          // 16 x 16 x 4 columns of 16 x 16 x 64 voxels
#define CAP    128           // entries per (mask,column); mean ~32, Poisson tail negligible
#define NQ     2048          // u64 per column byte-grid (16*16*64 / 8)

// One thread per (mask, atom), 2D grid (x: atoms, y: mask) -> no div/mod.
// Push packed voxel index into every column the [i-2,i+2]^3 footprint touches.
__global__ void bin_kernel(const float* __restrict__ src,
                           const float* __restrict__ tgt,
                           const float* __restrict__ ox,
                           const float* __restrict__ oy,
                           const float* __restrict__ oz,
                           const float* __restrict__ vox,
                           unsigned* __restrict__ cnt,
                           unsigned* __restrict__ entries,
                           float* __restrict__ out,
                           int N)
{
    int a = blockIdx.x * blockDim.x + threadIdx.x;
    int m = blockIdx.y;          // 0 = src, 1 = tgt
    if (a == 0 && m == 0) *out = 0.0f;            // ordered before tile_kernel's atomicAdds
    if (a >= N) return;

    const float* c = m ? tgt : src;
    float vx = vox[0];
    int i0 = (int)floorf((c[a]         - ox[0]) / vx);
    int i1 = (int)floorf((c[N + a]     - oy[0]) / vx);
    int i2 = (int)floorf((c[2 * N + a] - oz[0]) / vx);
    if ((unsigned)i0 >= GDIM || (unsigned)i1 >= GDIM || (unsigned)i2 >= GDIM) return; // center_ok

    unsigned pk = (unsigned)i0 | ((unsigned)i1 << 8) | ((unsigned)i2 << 16);
    int tlx = max(i0 - 2, 0) >> 4, thx = min(i0 + 2, GDIM - 1) >> 4;
    int tly = max(i1 - 2, 0) >> 4, thy = min(i1 + 2, GDIM - 1) >> 4;
    int tlz = max(i2 - 2, 0) >> 6, thz = min(i2 + 2, GDIM - 1) >> 6;

    for (int tx = tlx; tx <= thx; ++tx)
        for (int ty = tly; ty <= thy; ++ty)
            for (int tz = tlz; tz <= thz; ++tz) {
                int bin = m * NCOLS + (((tx << 4) + ty) << 2) + tz;
                unsigned slot = atomicAdd(&cnt[bin], 1u);
                if (slot < CAP) entries[bin * CAP + slot] = pk;
            }
}

// One block per 16x16x64 column: zero LDS src+tgt byte-grids (32 KiB), splat staged
// entries with the 21 (o0,o1) offsets split into 4 WAVE-UNIFORM groups (scalar branch,
// no exec-mask divergence; all 4 waves work instead of 1), then a branchless SWAR
// scan: per-byte min-d2 via lsb-isolate + popcounts. Cross term (src AND tgt cover
// the same byte, ~0.85% of bytes) in a rare loop with one LDS product-table read.
__global__ __launch_bounds__(256, 4)
void tile_kernel(const unsigned* __restrict__ cnt,
                 const unsigned* __restrict__ entries,
                 float* __restrict__ out)
{
    __shared__ unsigned long long smem[2 * NQ];   // [0,NQ) src, [NQ,2NQ) tgt : 32 KiB
    __shared__ unsigned eS[CAP], eT[CAP];
    __shared__ float tblp[49];                    // tblp[a*7+b] = exp(-K a) * exp(-K b)
    __shared__ float wsum[4];

    // 21 (o0,o1) offsets with o0^2+o1^2 <= 5, as compile-time constants.
    constexpr int OX[21] = {-2,-2,-2,-1,-1,-1,-1,-1, 0, 0, 0, 0, 0, 1, 1, 1, 1, 1, 2, 2, 2};
    constexpr int OY[21] = {-1, 0, 1,-2,-1, 0, 1, 2,-2,-1, 0, 1, 2,-2,-1, 0, 1, 2,-1, 0, 1};
    // Packed 5-byte z-row patterns: byte k (LE) = offset o2 = k-2, value (1 << d2) if d2 <= 6.
    constexpr unsigned long long PATC[21] = {
        0x0040204000ull, 0x0020102000ull, 0x0040204000ull,
        0x0040204000ull, 0x4008040840ull, 0x2004020420ull, 0x4008040840ull, 0x0040204000ull,
        0x0020102000ull, 0x2004020420ull, 0x1002010210ull, 0x2004020420ull, 0x0020102000ull,
        0x0040204000ull, 0x4008040840ull, 0x2004020420ull, 0x4008040840ull, 0x0040204000ull,
        0x0040204000ull, 0x0020102000ull, 0x0040204000ull,
    };

    int tid = threadIdx.x;
    int t   = blockIdx.x;
    int cx0 = (t >> 6) << 4;
    int cy0 = ((t >> 2) & 15) << 4;
    int cz0 = (t & 3) << 6;

    const float kf = (float)((3.14159265358979323846 / 3.5) * (3.14159265358979323846 / 3.5));
    if (tid < 49) {
        int a = tid / 7, b = tid - 7 * a;
        tblp[tid] = expf(-kf * (float)a) * expf(-kf * (float)b);
    }
    {   // zero 32 KiB of LDS: 2048 uint4
        uint4* zp = (uint4*)smem;
        #pragma unroll
        for (int i = 0; i < 8; ++i) zp[tid + i * 256] = make_uint4(0u, 0u, 0u, 0u);
    }
    int nS = min(cnt[t],         (unsigned)CAP);
    int nT = min(cnt[NCOLS + t], (unsigned)CAP);
    if (tid < nS) eS[tid] = entries[t * CAP + tid];              // nS,nT <= 128 < 256
    if (tid < nT) eT[tid] = entries[(NCOLS + t) * CAP + tid];
    __syncthreads();

    // ---- splat: wave w handles offset-group w for ALL entries (wave-uniform branch) ----
#define SPLAT_R(r) {                                                              \
        int l0 = x0 + OX[r];                                                      \
        int l1 = y0 + OY[r];                                                      \
        if ((unsigned)l0 < 16u && (unsigned)l1 < 16u) {                           \
            unsigned long long pat = (PATC[r] >> (8 * drop)) & kmask;             \
            if (pat) {                                                            \
                unsigned long long* q = base + (((l0 << 10) | (l1 << 6) | zb) >> 3); \
                unsigned long long lo = pat << (8 * off);                         \
                if (lo) atomicOr(q, lo);                                          \
                if (spill) {                                                      \
                    unsigned long long hi = pat >> (8 * (8 - off));               \
                    if (hi) atomicOr(q + 1, hi);                                  \
                }                                                                 \
            }                                                                     \
        }                                                                         \
    }
    {
        int lane = tid & 63, wv = tid >> 6;      // wv uniform per wave
        int nTot = nS + nT;
        for (int e = lane; e < nTot; e += 64) {
            int m        = e >= nS;
            unsigned pk  = m ? eT[e - nS] : eS[e];
            int i0 = pk & 255, i1 = (pk >> 8) & 255, i2 = (pk >> 16) & 255;
            int zs   = max(i2 - 2, cz0), ze = min(i2 + 2, cz0 + 63); // binned => zs <= ze
            int drop = zs - (i2 - 2), keep = ze - zs + 1;            // keep in [1,5]
            int zb   = zs - cz0;
            int off  = zb & 7;
            unsigned long long kmask = (1ull << (8 * keep)) - 1ull;
            int x0 = i0 - cx0, y0 = i1 - cy0;
            unsigned long long* base = smem + m * NQ;
            bool spill = (off + keep) > 8;                           // off >= 4 when true
            if (wv == 0) {
                SPLAT_R(0) SPLAT_R(1) SPLAT_R(2) SPLAT_R(3) SPLAT_R(4) SPLAT_R(5)
            } else if (wv == 1) {
                SPLAT_R(6) SPLAT_R(7) SPLAT_R(8) SPLAT_R(9) SPLAT_R(10) SPLAT_R(11)
            } else if (wv == 2) {
                SPLAT_R(12) SPLAT_R(13) SPLAT_R(14) SPLAT_R(15) SPLAT_R(16)
            } else {
                SPLAT_R(17) SPLAT_R(18) SPLAT_R(19) SPLAT_R(20)
            }
        }
    }
#undef SPLAT_R
    __syncthreads();

    // ---- scan: branchless SWAR min-d2 histogram + rare cross-term loop ----
    const unsigned long long H  = 0x8080808080808080ull;
    const unsigned long long B1 = 0x0101010101010101ull;
    const unsigned long long K7 = 0x7f7f7f7f7f7f7f7full;
    const ulonglong2* sp = (const ulonglong2*)smem;
    const ulonglong2* tp = (const ulonglong2*)(smem + NQ);

    ulonglong2 sv[4], tw[4];                       // issue all 8 ds_read_b128 up front
    #pragma unroll
    for (int i = 0; i < 4; ++i) {
        sv[i] = sp[tid + i * 256];
        tw[i] = tp[tid + i * 256];
    }

    int cd[7] = {0, 0, 0, 0, 0, 0, 0};             // static-indexed -> registers
    float accC = 0.0f;
    #pragma unroll
    for (int i = 0; i < 4; ++i) {
        #pragma unroll
        for (int k = 0; k < 2; ++k) {
            unsigned long long w = k ? sv[i].y : sv[i].x;
            unsigned long long v = k ? tw[i].y : tw[i].x;
            // per-byte lowest set bit (data bytes <= 0x7F; empty byte -> 0x80 sentinel)
            unsigned long long q   = w | H;
            unsigned long long lsb = q & (~q + B1);              // no cross-byte carries
            #pragma unroll
            for (int d = 0; d < 7; ++d)
                cd[d] += __popcll(lsb & (B1 << d));              // bytes with min d2 == d
            // bytes where BOTH src and tgt are covered (rare): subtract vs*vt
            unsigned long long bth = ((w + K7) & H) & ((v + K7) & H);
            while (bth) {
                int bit = __ffsll((long long)bth) - 1;           // = 8*byte + 7
                int sh  = bit & ~7;
                int ds  = __ffs((int)((unsigned)(w >> sh) & 0x7fu)) - 1;
                int dt  = __ffs((int)((unsigned)(v >> sh) & 0x7fu)) - 1;
                accC += tblp[ds * 7 + dt];
                bth &= bth - 1;
            }
        }
    }
    float acc = -accC;
    #pragma unroll
    for (int d = 0; d < 7; ++d) {
        float tv = expf(-kf * (float)d);           // same device expf values as tblp
        acc = fmaf((float)cd[d], tv * tv, acc);    // + count_d * tbl[d]^2
    }

    #pragma unroll
    for (int off2 = 32; off2 > 0; off2 >>= 1)
        acc += __shfl_down(acc, off2, 64);
    int lane = tid & 63, wv = tid >> 6;
    if (lane == 0) wsum[wv] = acc;
    __syncthreads();
    if (tid == 0)
        atomicAdd(out, wsum[0] + wsum[1] + wsum[2] + wsum[3]);
}

extern "C" void kernel_launch(void* const* d_in, const int* in_sizes, int n_in,
                              void* d_out, int out_size, void* d_ws, size_t ws_size,
                              hipStream_t stream)
{
    const float* src = (const float*)d_in[0];   // (1,3,N): [dim][atom]
    const float* tgt = (const float*)d_in[1];
    const float* ox  = (const float*)d_in[2];
    const float* oy  = (const float*)d_in[3];
    const float* oz  = (const float*)d_in[4];
    const float* vox = (const float*)d_in[5];
    int N = in_sizes[0] / 3;

    unsigned* cnt     = (unsigned*)d_ws;                 // 2*1024 counters (8 KiB)
    unsigned* entries = cnt + 2 * NCOLS;                 // 2*1024*128 u32 (1 MiB)

    hipMemsetAsync(cnt, 0, 2 * NCOLS * sizeof(unsigned), stream);

    dim3 bgrid((N + 255) / 256, 2);
    bin_kernel<<<bgrid, 256, 0, stream>>>(src, tgt, ox, oy, oz, vox, cnt, entries,
                                          (float*)d_out, N);
    tile_kernel<<<NCOLS, 256, 0, stream>>>(cnt, entries, (float*)d_out);
}